// Round 2
// baseline (11795.690 us; speedup 1.0000x reference)
//
#include <hip/hip_runtime.h>
#include <stdint.h>

// LSTM B=32,T=512,D=1024,H=1024. 2 groups x 16 batches; 128 blocks/group.
// Block = 512 thr (8 waves), owns 8 h-cols (=32 gate cols). Wx/Wh slice
// pre-fragmented in 128KB LDS. Full M=16 MFMA (batches = rows). Per-step
// h exchange: plain stores + agent release fence + flag; poll + acquire fence.

typedef _Float16 f16;
typedef __attribute__((ext_vector_type(8))) _Float16 f16x8;
typedef __attribute__((ext_vector_type(4))) float f32x4;
typedef __attribute__((ext_vector_type(4))) unsigned int u32x4;

#define NG 2
#define BPG 128
#define NW 8

__device__ __forceinline__ float sigm(float v){ return 1.f/(1.f+__expf(-v)); }
__device__ __forceinline__ float tanh_(float v){ return 2.f/(1.f+__expf(-2.f*v)) - 1.f; }

__global__ __launch_bounds__(512, 2) void lstm_kernel(
    const float* __restrict__ xin, const float* __restrict__ amask,
    const int* __restrict__ nzidx, const float* __restrict__ Wx,
    const float* __restrict__ Wh, const float* __restrict__ bx,
    const float* __restrict__ bh, float* __restrict__ out,
    uint32_t* __restrict__ ws)
{
  // frag f = side*64 + kf*2 + nt  (side: 0=x,1=h; kf 0..31; nt 0..1)
  __shared__ __align__(16) f16 Wl[128][64][8];      // 128 KB
  __shared__ __align__(16) float pl[NW][2][64][4];  // 16 KB
  __shared__ __align__(16) f16 hstage[16][8];       // 256 B

  const int tid  = threadIdx.x;
  const int lane = tid & 63;
  const int wid  = tid >> 6;
  const int r    = blockIdx.x & 127;   // rank in group
  const int G    = blockIdx.x >> 7;    // group
  const int hbase = r * 8;             // this block's h-cols [hbase, hbase+8)

  uint32_t* flags = ws + (size_t)G * BPG;          // [NG][128] u32
  f16* hb = (f16*)(ws + 2 * BPG);                  // [2][NG][32][64][8] f16 = 128 KB

  // ---- prologue: W slice -> LDS frags ----
  for (int f = wid; f < 128; f += NW) {
    const int side = f >> 6, kf = (f >> 1) & 31, nt = f & 1;
    const int c16 = lane & 15, kslot = lane >> 4;
    const int g = nt * 2 + (c16 >> 3);
    const int gcol = g * 1024 + hbase + (c16 & 7);
    const int k0 = kf * 32 + kslot * 8;
    const float* Wsrc = side ? Wh : Wx;
    f16x8 v;
#pragma unroll
    for (int e = 0; e < 8; ++e) v[e] = (f16)Wsrc[(size_t)(k0 + e) * 4096 + gcol];
    *(f16x8*)&Wl[f][lane][0] = v;
  }
  // owner state (tid<128): owner = (batch b, h-col hc)
  const int b  = tid >> 3;      // 0..15
  const int hc = tid & 7;       // 0..7
  const int b_glob = G * 16 + b;
  float bias[4] = {0.f, 0.f, 0.f, 0.f};
  float cval = 0.f;
  int myidx = -1;
  if (tid < 128) {
#pragma unroll
    for (int g = 0; g < 4; ++g) {
      const int gcol = g * 1024 + hbase + hc;
      bias[g] = bx[gcol] + bh[gcol];
    }
    myidx = nzidx[b_glob];
  }
  __syncthreads();

  bool gave_up = false;
#pragma unroll 1
  for (int t = 0; t < 512; ++t) {
    f32x4 acc0 = {0.f,0.f,0.f,0.f}, acc1 = {0.f,0.f,0.f,0.f};
    const int bb = lane & 15, kslot = lane >> 4;
    // ---- x-side: A from global (f32->f16), B from LDS frags ----
    {
      const size_t xrow = ((size_t)(G * 16 + bb) * 512 + (size_t)t) * 1024;
#pragma unroll
      for (int q = 0; q < 4; ++q) {
        const int kf = wid * 4 + q;
        const int k0 = kf * 32 + kslot * 8;
        const float* xs = xin + xrow + k0;
        f16x8 a;
#pragma unroll
        for (int e = 0; e < 8; ++e) a[e] = (f16)xs[e];
        f16x8 b0 = *(const f16x8*)&Wl[kf * 2 + 0][lane][0];
        f16x8 b1 = *(const f16x8*)&Wl[kf * 2 + 1][lane][0];
        acc0 = __builtin_amdgcn_mfma_f32_16x16x32_f16(a, b0, acc0, 0, 0, 0);
        acc1 = __builtin_amdgcn_mfma_f32_16x16x32_f16(a, b1, acc1, 0, 0, 0);
      }
    }
    // ---- h-side (t>0): wait my 16 producers, then A from hbuf ----
    if (t > 0) {
      if (!gave_up) {
        const uint32_t tgt = (uint32_t)t;
        int spins = 0;
        for (;;) {
          uint32_t fv = (lane < 16)
            ? __hip_atomic_load(&flags[wid * 16 + lane], __ATOMIC_RELAXED, __HIP_MEMORY_SCOPE_AGENT)
            : tgt;
          if (__all((int)(fv >= tgt))) break;
          if (++spins > (1 << 18)) { gave_up = true; break; }
          __builtin_amdgcn_s_sleep(2);
        }
        __builtin_amdgcn_fence(__ATOMIC_ACQUIRE, "agent");
      }
      const int p = t & 1;
      const f16* hsrc = hb + ((size_t)(p * NG + G) * 2048) * 8;  // 2048 = 32*64
#pragma unroll
      for (int q = 0; q < 4; ++q) {
        const int kf = wid * 4 + q;
        f16x8 a = *(const f16x8*)(hsrc + (size_t)(kf * 64 + lane) * 8);
        f16x8 b0 = *(const f16x8*)&Wl[64 + kf * 2 + 0][lane][0];
        f16x8 b1 = *(const f16x8*)&Wl[64 + kf * 2 + 1][lane][0];
        acc0 = __builtin_amdgcn_mfma_f32_16x16x32_f16(a, b0, acc0, 0, 0, 0);
        acc1 = __builtin_amdgcn_mfma_f32_16x16x32_f16(a, b1, acc1, 0, 0, 0);
      }
    }
    *(f32x4*)&pl[wid][0][lane][0] = acc0;
    *(f32x4*)&pl[wid][1][lane][0] = acc1;
    __syncthreads();  // pl ready
    // ---- owners: reduce, gates, state, outputs ----
    if (tid < 128) {
      float s[4];
#pragma unroll
      for (int g = 0; g < 4; ++g) {
        const int nt = g >> 1;
        const int lp = ((g & 1) * 8 + hc) + 16 * (b >> 2);
        const int reg = b & 3;
        float v = bias[g];
#pragma unroll
        for (int w = 0; w < NW; ++w) v += pl[w][nt][lp][reg];
        s[g] = v;
      }
      const float ig = sigm(s[0]);
      const float fg = sigm(s[1]);
      const float gg = tanh_(s[2]);
      const float og = sigm(s[3]);
      cval = fg * cval + ig * gg;
      const float hval = og * tanh_(cval);
      hstage[b][hc] = (f16)hval;
      const float mval = amask[(size_t)b_glob * 512 + (size_t)t];
      const size_t o0 = ((size_t)b_glob * 512 + (size_t)t) * 1024 + (size_t)(hbase + hc);
      out[o0] = hval * mval;                   // hts copy 1
      out[o0 + 16777216u] = hval * mval;       // hts copy 2
      out[o0 + 33554432u] = cval * mval;       // cts
      if (t == myidx) out[50331648u + (size_t)b_glob * 1024 + (size_t)(hbase + hc)] = hval;
    }
    __syncthreads();  // hstage ready
    // ---- publish h: wave0 stores 16B/batch, release fence, flag ----
    if (wid == 0 && lane < 16) {
      const int p2 = (t + 1) & 1;
      u32x4 v = *(const u32x4*)&hstage[lane][0];
      f16* dst = hb + ((size_t)(p2 * NG + G) * 2048 + (size_t)((r >> 2) * 64 + lane + 16 * (r & 3))) * 8;
      *(u32x4*)dst = v;
    }
    if (wid == 0) {
      __builtin_amdgcn_fence(__ATOMIC_RELEASE, "agent");
      if (lane == 0)
        __hip_atomic_store(&flags[r], (uint32_t)(t + 1), __ATOMIC_RELAXED, __HIP_MEMORY_SCOPE_AGENT);
    }
  }
}

extern "C" void kernel_launch(void* const* d_in, const int* in_sizes, int n_in,
                              void* d_out, int out_size, void* d_ws, size_t ws_size,
                              hipStream_t stream) {
  const float* xin   = (const float*)d_in[0];
  const float* amask = (const float*)d_in[1];
  const int*   nzidx = (const int*)d_in[2];
  const float* Wx    = (const float*)d_in[3];
  const float* Wh    = (const float*)d_in[4];
  const float* bx    = (const float*)d_in[5];
  const float* bh    = (const float*)d_in[6];
  float* out = (float*)d_out;
  uint32_t* ws = (uint32_t*)d_ws;

  // zero the flag region every launch (graph-replay safe)
  hipMemsetAsync(d_ws, 0, 2 * BPG * sizeof(uint32_t), stream);

  void* args[] = {(void*)&xin, (void*)&amask, (void*)&nzidx, (void*)&Wx,
                  (void*)&Wh, (void*)&bx, (void*)&bh, (void*)&out, (void*)&ws};
  hipError_t e = hipLaunchCooperativeKernel((const void*)lstm_kernel, dim3(256), dim3(512),
                                            args, 0, stream);
  if (e != hipSuccess) {
    lstm_kernel<<<dim3(256), dim3(512), 0, stream>>>(xin, amask, nzidx, Wx, Wh, bx, bh, out, ws);
  }
}

// Round 3
// 2157.976 us; speedup vs baseline: 5.4661x; 5.4661x over previous
//
#include <hip/hip_runtime.h>
#include <stdint.h>

// LSTM B=32,T=512,D=1024,H=1024. 2 groups x 16 batches; 128 blocks/group.
// Block = 512 thr (8 waves), owns 8 h-cols (=32 gate cols). Wx/Wh slice
// pre-fragmented in 128KB LDS. Full M=16 MFMA (batches = rows).
// Per-step h exchange: relaxed AGENT-scope atomics (sc1, cache-bypass) for
// h data + flags; ordering via s_waitcnt vmcnt(0) before flag store.
// NO fences -> no per-step buffer_wbl2/buffer_inv L2-maintenance walks
// (round-2's 24us/step stall).

typedef _Float16 f16;
typedef __attribute__((ext_vector_type(8))) _Float16 f16x8;
typedef __attribute__((ext_vector_type(4))) float f32x4;

#define NG 2
#define BPG 128
#define NW 8

__device__ __forceinline__ float sigm(float v){ return 1.f/(1.f+__expf(-v)); }
__device__ __forceinline__ float tanh_(float v){ return 2.f/(1.f+__expf(-2.f*v)) - 1.f; }

__global__ __launch_bounds__(512, 2) void lstm_kernel(
    const float* __restrict__ xin, const float* __restrict__ amask,
    const int* __restrict__ nzidx, const float* __restrict__ Wx,
    const float* __restrict__ Wh, const float* __restrict__ bx,
    const float* __restrict__ bh, float* __restrict__ out,
    uint32_t* __restrict__ ws)
{
  // frag f = side*64 + kf*2 + nt  (side: 0=x,1=h; kf 0..31; nt 0..1)
  __shared__ __align__(16) f16 Wl[128][64][8];      // 128 KB
  __shared__ __align__(16) float pl[NW][2][64][4];  // 16 KB
  __shared__ __align__(16) f16 hstage[16][8];       // 256 B

  const int tid  = threadIdx.x;
  const int lane = tid & 63;
  const int wid  = tid >> 6;
  const int r    = blockIdx.x & 127;   // rank in group
  const int G    = blockIdx.x >> 7;    // group
  const int hbase = r * 8;             // this block's h-cols [hbase, hbase+8)

  uint32_t* flags = ws + (size_t)G * BPG;          // [NG][128] u32
  uint64_t* hb64 = (uint64_t*)(ws + 2 * BPG);      // [2][NG][2048 elems][2 u64] = 128 KB

  // ---- prologue: W slice -> LDS frags ----
  for (int f = wid; f < 128; f += NW) {
    const int side = f >> 6, kf = (f >> 1) & 31, nt = f & 1;
    const int c16 = lane & 15, kslot = lane >> 4;
    const int g = nt * 2 + (c16 >> 3);
    const int gcol = g * 1024 + hbase + (c16 & 7);
    const int k0 = kf * 32 + kslot * 8;
    const float* Wsrc = side ? Wh : Wx;
    f16x8 v;
#pragma unroll
    for (int e = 0; e < 8; ++e) v[e] = (f16)Wsrc[(size_t)(k0 + e) * 4096 + gcol];
    *(f16x8*)&Wl[f][lane][0] = v;
  }
  // owner state (tid<128): owner = (batch b, h-col hc)
  const int b  = tid >> 3;      // 0..15
  const int hc = tid & 7;       // 0..7
  const int b_glob = G * 16 + b;
  float bias[4] = {0.f, 0.f, 0.f, 0.f};
  float cval = 0.f;
  int myidx = -1;
  if (tid < 128) {
#pragma unroll
    for (int g = 0; g < 4; ++g) {
      const int gcol = g * 1024 + hbase + hc;
      bias[g] = bx[gcol] + bh[gcol];
    }
    myidx = nzidx[b_glob];
  }
  __syncthreads();

  bool gave_up = false;
#pragma unroll 1
  for (int t = 0; t < 512; ++t) {
    f32x4 acc0 = {0.f,0.f,0.f,0.f}, acc1 = {0.f,0.f,0.f,0.f};
    const int bb = lane & 15, kslot = lane >> 4;
    // ---- x-side: A from global (f32->f16), B from LDS frags ----
    {
      const size_t xrow = ((size_t)(G * 16 + bb) * 512 + (size_t)t) * 1024;
#pragma unroll
      for (int q = 0; q < 4; ++q) {
        const int kf = wid * 4 + q;
        const int k0 = kf * 32 + kslot * 8;
        const float* xs = xin + xrow + k0;
        f16x8 a;
#pragma unroll
        for (int e = 0; e < 8; ++e) a[e] = (f16)xs[e];
        f16x8 b0 = *(const f16x8*)&Wl[kf * 2 + 0][lane][0];
        f16x8 b1 = *(const f16x8*)&Wl[kf * 2 + 1][lane][0];
        acc0 = __builtin_amdgcn_mfma_f32_16x16x32_f16(a, b0, acc0, 0, 0, 0);
        acc1 = __builtin_amdgcn_mfma_f32_16x16x32_f16(a, b1, acc1, 0, 0, 0);
      }
    }
    // ---- h-side (t>0): wait my 16 producers, then A from hb (atomic loads) ----
    if (t > 0) {
      if (!gave_up) {
        const uint32_t tgt = (uint32_t)t;
        int spins = 0;
        for (;;) {
          uint32_t fv = (lane < 16)
            ? __hip_atomic_load(&flags[wid * 16 + lane], __ATOMIC_RELAXED, __HIP_MEMORY_SCOPE_AGENT)
            : tgt;
          if (__all((int)(fv >= tgt))) break;
          if (++spins > (1 << 16)) { gave_up = true; break; }  // latched hang safety
          __builtin_amdgcn_s_sleep(1);
        }
        __builtin_amdgcn_sched_barrier(0);  // pin h loads after poll exit
      }
      const int p = t & 1;
      const uint64_t* hsrc = hb64 + (size_t)(p * NG + G) * 4096;
#pragma unroll
      for (int q = 0; q < 4; ++q) {
        const int kf = wid * 4 + q;
        const size_t e2 = (size_t)(kf * 64 + lane) * 2;
        uint64_t lo = __hip_atomic_load(hsrc + e2,     __ATOMIC_RELAXED, __HIP_MEMORY_SCOPE_AGENT);
        uint64_t hi = __hip_atomic_load(hsrc + e2 + 1, __ATOMIC_RELAXED, __HIP_MEMORY_SCOPE_AGENT);
        union { uint64_t u[2]; f16x8 v; } cv;
        cv.u[0] = lo; cv.u[1] = hi;
        f16x8 b0 = *(const f16x8*)&Wl[64 + kf * 2 + 0][lane][0];
        f16x8 b1 = *(const f16x8*)&Wl[64 + kf * 2 + 1][lane][0];
        acc0 = __builtin_amdgcn_mfma_f32_16x16x32_f16(cv.v, b0, acc0, 0, 0, 0);
        acc1 = __builtin_amdgcn_mfma_f32_16x16x32_f16(cv.v, b1, acc1, 0, 0, 0);
      }
    }
    *(f32x4*)&pl[wid][0][lane][0] = acc0;
    *(f32x4*)&pl[wid][1][lane][0] = acc1;
    __syncthreads();  // sync1: pl ready
    // ---- owners: reduce, gates, state ----
    float hval = 0.f, mval = 0.f;
    if (tid < 128) {
      float s[4];
#pragma unroll
      for (int g = 0; g < 4; ++g) {
        const int nt = g >> 1;
        const int lp = ((g & 1) * 8 + hc) + 16 * (b >> 2);
        const int reg = b & 3;
        float v = bias[g];
#pragma unroll
        for (int w = 0; w < NW; ++w) v += pl[w][nt][lp][reg];
        s[g] = v;
      }
      const float ig = sigm(s[0]);
      const float fg = sigm(s[1]);
      const float gg = tanh_(s[2]);
      const float og = sigm(s[3]);
      cval = fg * cval + ig * gg;
      hval = og * tanh_(cval);
      hstage[b][hc] = (f16)hval;
      mval = amask[(size_t)b_glob * 512 + (size_t)t];
    }
    __syncthreads();  // sync2: hstage ready
    // ---- publish FIRST (critical path for the other 127 blocks) ----
    if (wid == 0) {
      if (lane < 32) {
        const int p2 = (t + 1) & 1;
        const uint64_t v = ((const uint64_t*)hstage)[lane];   // b'=lane>>1, half=lane&1
        const size_t e = (size_t)((r >> 2) * 64 + (r & 3) * 16 + (lane >> 1));
        __hip_atomic_store(hb64 + (size_t)(p2 * NG + G) * 4096 + e * 2 + (lane & 1), v,
                           __ATOMIC_RELAXED, __HIP_MEMORY_SCOPE_AGENT);
      }
      asm volatile("s_waitcnt vmcnt(0)" ::: "memory");  // h at coherence point
      if (lane == 0)
        __hip_atomic_store(&flags[r], (uint32_t)(t + 1), __ATOMIC_RELAXED, __HIP_MEMORY_SCOPE_AGENT);
    }
    // ---- output stores (fire-and-forget, off the sync critical path) ----
    if (tid < 128) {
      const size_t o0 = ((size_t)b_glob * 512 + (size_t)t) * 1024 + (size_t)(hbase + hc);
      out[o0] = hval * mval;                   // hts copy 1
      out[o0 + 16777216u] = hval * mval;       // hts copy 2
      out[o0 + 33554432u] = cval * mval;       // cts
      if (t == myidx) out[50331648u + (size_t)b_glob * 1024 + (size_t)(hbase + hc)] = hval;
    }
  }
}

extern "C" void kernel_launch(void* const* d_in, const int* in_sizes, int n_in,
                              void* d_out, int out_size, void* d_ws, size_t ws_size,
                              hipStream_t stream) {
  const float* xin   = (const float*)d_in[0];
  const float* amask = (const float*)d_in[1];
  const int*   nzidx = (const int*)d_in[2];
  const float* Wx    = (const float*)d_in[3];
  const float* Wh    = (const float*)d_in[4];
  const float* bx    = (const float*)d_in[5];
  const float* bh    = (const float*)d_in[6];
  float* out = (float*)d_out;
  uint32_t* ws = (uint32_t*)d_ws;

  // zero the flag region every launch (graph-replay safe)
  hipMemsetAsync(d_ws, 0, 2 * BPG * sizeof(uint32_t), stream);

  void* args[] = {(void*)&xin, (void*)&amask, (void*)&nzidx, (void*)&Wx,
                  (void*)&Wh, (void*)&bx, (void*)&bh, (void*)&out, (void*)&ws};
  hipError_t e = hipLaunchCooperativeKernel((const void*)lstm_kernel, dim3(256), dim3(512),
                                            args, 0, stream);
  if (e != hipSuccess) {
    lstm_kernel<<<dim3(256), dim3(512), 0, stream>>>(xin, amask, nzidx, Wx, Wh, bx, bh, out, ws);
  }
}